// Round 6
// baseline (143.660 us; speedup 1.0000x reference)
//
#include <hip/hip_runtime.h>
#include <math.h>

#define TB 2
#define TT 2048
#define NH 16
#define HD 64
#define HSZ 1024

typedef float floatx4 __attribute__((ext_vector_type(4)));
typedef __bf16 bf16x4 __attribute__((ext_vector_type(4)));
typedef __bf16 bf16x8 __attribute__((ext_vector_type(8)));

#define LOG2E  1.4426950408889634f
#define NEGF   (-0.4152410118609203f)   // -log2(10000)/32
#define INV2PI 0.15915494309189535f

// ============ phase 1: fused prep — RoPE-K pack + V transpose-pack ============
// XCD-swizzled so tile (bh,kt) is WRITTEN on XCD bh/4 — the same XCD whose
// attn blocks read it (attn swizzle also maps bh -> XCD bh/4). Previously
// prep wrote tile kt on XCD kt%8 -> attn reads were remote (L3-served).
__global__ __launch_bounds__(256)
void prep_kernel(const float* __restrict__ K, const float* __restrict__ V,
                 __bf16* __restrict__ Kp, __bf16* __restrict__ Vp) {
    int blk0 = blockIdx.x;
    int blk = ((blk0 & 7) << 7) + (blk0 >> 3);   // bijective, 1024 % 8 == 0
    int kt = blk & 31;
    int bh = blk >> 5;
    int b = bh >> 4, h = bh & 15;
    int tid = threadIdx.x;

    // ---- K part: thread -> (key=tid>>2, dim-octet qq=tid&3) ----
    {
        int key = tid >> 2, qq = tid & 3;
        int tglob = kt * 64 + key;
        const float* krow = K + ((size_t)(b * TT + tglob)) * HSZ + h * HD + qq * 8;
        float x0[8], x1[8];
        *(floatx4*)&x0[0] = *(const floatx4*)&krow[0];
        *(floatx4*)&x0[4] = *(const floatx4*)&krow[4];
        *(floatx4*)&x1[0] = *(const floatx4*)&krow[32];
        *(floatx4*)&x1[4] = *(const floatx4*)&krow[36];
        bf16x8 y0, y1;
        #pragma unroll
        for (int j = 0; j < 8; ++j) {
            float freq = exp2f((float)(qq * 8 + j) * NEGF);
            float rv = (float)tglob * freq * INV2PI;
            rv -= floorf(rv);
            float s = __builtin_amdgcn_sinf(rv);
            float c = __builtin_amdgcn_cosf(rv);
            y0[j] = (__bf16)(x0[j] * c - x1[j] * s);
            y1[j] = (__bf16)(x1[j] * c + x0[j] * s);
        }
        size_t base = ((size_t)blk * 4 + (key & 3)) * 1024 + (size_t)(qq * 16 + (key >> 2)) * 8;
        *(bf16x8*)(Kp + base)       = y0;
        *(bf16x8*)(Kp + base + 512) = y1;
    }

    // ---- V part: transpose 64x64 via LDS ----
    __shared__ __bf16 lt[64][72];
    {
        int vkey = tid >> 2, dg = (tid & 3) * 16;
        const float* vrow = V + ((size_t)(b * TT + kt * 64 + vkey)) * HSZ + h * HD + dg;
        floatx4 v0 = *(const floatx4*)&vrow[0];
        floatx4 v1 = *(const floatx4*)&vrow[4];
        floatx4 v2 = *(const floatx4*)&vrow[8];
        floatx4 v3 = *(const floatx4*)&vrow[12];
        #pragma unroll
        for (int j = 0; j < 4; ++j) {
            lt[dg + j][vkey]      = (__bf16)v0[j];
            lt[dg + 4 + j][vkey]  = (__bf16)v1[j];
            lt[dg + 8 + j][vkey]  = (__bf16)v2[j];
            lt[dg + 12 + j][vkey] = (__bf16)v3[j];
        }
    }
    __syncthreads();
    #pragma unroll
    for (int ss = 0; ss < 2; ++ss) {
        int s = tid + ss * 256;
        int hg = s >> 6;
        int l = s & 63;
        int lq = l >> 4, lr = l & 15;
        int h2 = hg >> 2, g = hg & 3;
        bf16x8 o = *(const bf16x8*)&lt[g * 16 + lr][h2 * 32 + lq * 8];
        *(bf16x8*)(Vp + (size_t)blk * 4096 + (size_t)hg * 512 + (size_t)l * 8) = o;
    }
}

// ============ phase 2: flash attention, LDS-staged K/V, 32 q-rows/wave ============
// K/V tiles staged ONCE per block into LDS via global_load_lds (linear layout
// = byte-copy of the packed tile; ds_read_b128 lane*16 is conflict-free).
// Rationale: attn was invariant to occupancy/LDS/sched changes; per-wave
// redundant K/V loads pushed 1.07 GB through the (remote) L2/L3 path at
// 18.4 TB/s — the shared-path bound. Staging cuts that 4x and prefetches
// one tile ahead under compute. s_setprio(1) around MFMA clusters (T5,
// isolated this time).
__global__ __launch_bounds__(256, 2)
void attn_kernel(const float* __restrict__ Q, const __bf16* __restrict__ Kp,
                 const __bf16* __restrict__ Vp, float* __restrict__ Out) {
    // bijective XCD swizzle (512 % 8 == 0): same-bh blocks share an XCD L2.
    int blk0 = blockIdx.x;
    int blk = (blk0 & 7) * 64 + (blk0 >> 3);

    int qb = blk & 15;                  // 16 q-blocks of 128 rows
    int bh = blk >> 4;
    int b = bh >> 4, h = bh & 15;
    int tid = threadIdx.x;
    int wave = tid >> 6, lane = tid & 63;
    int lane15 = lane & 15, quad = lane >> 4;

    // double-buffered K/V tiles (8 KB K + 8 KB V each) + per-wave P tiles
    __shared__ __align__(16) unsigned char kvbuf[2][16384];
    __shared__ __align__(16) __bf16 sP[4][2][16][72];   // 18432 B; total 51200 B

    const float scale2 = 0.125f * LOG2E;
    const float slope2 = exp2f(-0.5f * (float)(h + 1)) * LOG2E;
    const float ms     = slope2 * 2047.0f + 20.0f;      // static log2-domain shift

    // ---- Q load + RoPE into 2 A-fragment pairs (32 q-rows/wave) ----
    int qbase = qb * 128 + wave * 32;
    int d0 = quad * 8;
    bf16x8 aQ0[2], aQ1[2];
    #pragma unroll
    for (int qf = 0; qf < 2; ++qf) {
        int t_q = qbase + qf * 16 + lane15;
        const float* qrow = Q + ((size_t)(b * TT + t_q) * HSZ) + h * HD;
        float q0[8], q1[8];
        *(floatx4*)&q0[0] = *(const floatx4*)&qrow[d0];
        *(floatx4*)&q0[4] = *(const floatx4*)&qrow[d0 + 4];
        *(floatx4*)&q1[0] = *(const floatx4*)&qrow[d0 + 32];
        *(floatx4*)&q1[4] = *(const floatx4*)&qrow[d0 + 36];
        #pragma unroll
        for (int j = 0; j < 8; ++j) {
            float freq = exp2f((float)(d0 + j) * NEGF);
            float rv = (float)t_q * freq * INV2PI;
            rv -= floorf(rv);
            float sn = __builtin_amdgcn_sinf(rv);
            float cs = __builtin_amdgcn_cosf(rv);
            aQ0[qf][j] = (__bf16)((q0[j] * cs - q1[j] * sn) * scale2);
            aQ1[qf][j] = (__bf16)((q1[j] * cs + q0[j] * sn) * scale2);
        }
    }

    float slk2[4];
    #pragma unroll
    for (int nt = 0; nt < 4; ++nt)
        slk2[nt] = slope2 * (float)(4 * lane15 + nt) - ms;
    const float dstep = slope2 * 64.0f;

    floatx4 O[2][4];
    float lrow[2][4];
    #pragma unroll
    for (int qf = 0; qf < 2; ++qf)
        #pragma unroll
        for (int r = 0; r < 4; ++r) {
            O[qf][r] = (floatx4){0.f, 0.f, 0.f, 0.f};
            lrow[qf][r] = 0.f;
        }

    const __bf16* KpT = Kp + (size_t)bh * (TT * HD);
    const __bf16* VpT = Vp + (size_t)bh * (TT * HD);

    // block-wide stage of tile kt_ into kvbuf[buf]: 16 KB via 4 DMA calls/thread-set
    auto stage = [&](int buf, int kt_) {
        const unsigned char* gk = (const unsigned char*)(KpT + (size_t)kt_ * 4096);
        const unsigned char* gv = (const unsigned char*)(VpT + (size_t)kt_ * 4096);
        unsigned char* lb = &kvbuf[buf][0];
        int wl = wave * 1024 + lane * 16;       // per-lane global offset
        int wb = wave * 1024;                   // wave-uniform LDS base offset
        #pragma unroll
        for (int c = 0; c < 2; ++c) {
            __builtin_amdgcn_global_load_lds(
                (const __attribute__((address_space(1))) unsigned int*)(gk + c * 4096 + wl),
                (__attribute__((address_space(3))) unsigned int*)(lb + c * 4096 + wb),
                16, 0, 0);
            __builtin_amdgcn_global_load_lds(
                (const __attribute__((address_space(1))) unsigned int*)(gv + c * 4096 + wl),
                (__attribute__((address_space(3))) unsigned int*)(lb + 8192 + c * 4096 + wb),
                16, 0, 0);
        }
    };

    stage(0, 0);
    __syncthreads();

    const int kt1 = TT / 64;            // 32 tiles, full sequence

    #pragma unroll 1
    for (int kt = 0; kt < kt1; ++kt) {
        int cur = kt & 1;
        // issue next tile's DMA first: it drains at the end-of-iter barrier,
        // with the whole compute phase to cover its latency.
        if (kt + 1 < kt1) stage(cur ^ 1, kt + 1);

        const unsigned char* kb = &kvbuf[cur][0];

        // ---- K fragments from LDS (conflict-free: lane*16 contiguous) ----
        bf16x8 bk[4][2];
        #pragma unroll
        for (int nt = 0; nt < 4; ++nt) {
            bk[nt][0] = *(const bf16x8*)(kb + nt * 2048 + lane * 16);
            bk[nt][1] = *(const bf16x8*)(kb + nt * 2048 + 1024 + lane * 16);
        }
        // ---- V fragments from LDS ----
        bf16x8 bv[2][4];
        #pragma unroll
        for (int hg = 0; hg < 8; ++hg)
            bv[hg >> 2][hg & 3] = *(const bf16x8*)(kb + 8192 + hg * 1024 + lane * 16);

        // ---- phase 1: QK^T + exp2 + sP, for both q-fragments ----
        float biask = dstep * (float)kt;
        #pragma unroll
        for (int qf = 0; qf < 2; ++qf) {
            float P[4][4];
            __builtin_amdgcn_s_setprio(1);
            #pragma unroll
            for (int nt = 0; nt < 4; ++nt) {
                floatx4 acc = {0.f, 0.f, 0.f, 0.f};
                acc = __builtin_amdgcn_mfma_f32_16x16x32_bf16(aQ0[qf], bk[nt][0], acc, 0, 0, 0);
                acc = __builtin_amdgcn_mfma_f32_16x16x32_bf16(aQ1[qf], bk[nt][1], acc, 0, 0, 0);
                float bias = slk2[nt] + biask;
                #pragma unroll
                for (int r = 0; r < 4; ++r)
                    P[nt][r] = __builtin_amdgcn_exp2f(acc[r] + bias);
            }
            __builtin_amdgcn_s_setprio(0);
            #pragma unroll
            for (int r = 0; r < 4; ++r) {
                lrow[qf][r] += (P[0][r] + P[1][r]) + (P[2][r] + P[3][r]);
                bf16x4 pp;
                pp[0] = (__bf16)P[0][r]; pp[1] = (__bf16)P[1][r];
                pp[2] = (__bf16)P[2][r]; pp[3] = (__bf16)P[3][r];
                *(bf16x4*)&sP[wave][qf][quad * 4 + r][4 * lane15] = pp;
            }
        }

        // ---- phase 2: PV for both q-fragments ----
        #pragma unroll
        for (int qf = 0; qf < 2; ++qf) {
            #pragma unroll
            for (int h2 = 0; h2 < 2; ++h2) {
                bf16x8 aP = *(const bf16x8*)&sP[wave][qf][lane15][h2 * 32 + quad * 8];
                __builtin_amdgcn_s_setprio(1);
                O[qf][0] = __builtin_amdgcn_mfma_f32_16x16x32_bf16(aP, bv[h2][0], O[qf][0], 0, 0, 0);
                O[qf][1] = __builtin_amdgcn_mfma_f32_16x16x32_bf16(aP, bv[h2][1], O[qf][1], 0, 0, 0);
                O[qf][2] = __builtin_amdgcn_mfma_f32_16x16x32_bf16(aP, bv[h2][2], O[qf][2], 0, 0, 0);
                O[qf][3] = __builtin_amdgcn_mfma_f32_16x16x32_bf16(aP, bv[h2][3], O[qf][3], 0, 0, 0);
                __builtin_amdgcn_s_setprio(0);
            }
        }

        // barrier: (a) staging DMAs for kt+1 drained, (b) all waves done
        // reading kvbuf[cur] before it is overwritten in iter kt+2.
        __syncthreads();
    }

    // ---- epilogue: reduce l, normalize in-register, write fp32 Out directly ----
    #pragma unroll
    for (int qf = 0; qf < 2; ++qf) {
        #pragma unroll
        for (int r = 0; r < 4; ++r) {
            float l = lrow[qf][r];
            l += __shfl_xor(l, 1);
            l += __shfl_xor(l, 2);
            l += __shfl_xor(l, 4);
            l += __shfl_xor(l, 8);
            float inv = 1.0f / l;
            int t = qbase + qf * 16 + quad * 4 + r;
            size_t base = ((size_t)(b * TT + t)) * HSZ + h * HD + lane15;
            Out[base +  0] = O[qf][0][r] * inv;
            Out[base + 16] = O[qf][1][r] * inv;
            Out[base + 32] = O[qf][2][r] * inv;
            Out[base + 48] = O[qf][3][r] * inv;
        }
    }
}

extern "C" void kernel_launch(void* const* d_in, const int* in_sizes, int n_in,
                              void* d_out, int out_size, void* d_ws, size_t ws_size,
                              hipStream_t stream) {
    const float* q = (const float*)d_in[0];
    const float* k = (const float*)d_in[1];
    const float* v = (const float*)d_in[2];
    float* out = (float*)d_out;

    char* ws = (char*)d_ws;
    __bf16* Kp = (__bf16*)ws;                                  // 8 MB
    __bf16* Vp = (__bf16*)(ws + (size_t)8 * 1024 * 1024);      // 8 MB

    prep_kernel<<<dim3(TB * NH * (TT / 64)), 256, 0, stream>>>(k, v, Kp, Vp);
    attn_kernel<<<dim3(TB * NH * 16), 256, 0, stream>>>(q, Kp, Vp, out);
}

// Round 7
// 127.256 us; speedup vs baseline: 1.1289x; 1.1289x over previous
//
#include <hip/hip_runtime.h>
#include <math.h>

#define TB 2
#define TT 2048
#define NH 16
#define HD 64
#define HSZ 1024

typedef float floatx4 __attribute__((ext_vector_type(4)));
typedef __bf16 bf16x4 __attribute__((ext_vector_type(4)));
typedef __bf16 bf16x8 __attribute__((ext_vector_type(8)));

#define LOG2E  1.4426950408889634f
#define NEGF   (-0.4152410118609203f)   // -log2(10000)/32
#define INV2PI 0.15915494309189535f

// ============ phase 1: fused prep — RoPE-K pack + V transpose-pack ============
__global__ __launch_bounds__(256)
void prep_kernel(const float* __restrict__ K, const float* __restrict__ V,
                 __bf16* __restrict__ Kp, __bf16* __restrict__ Vp) {
    int blk = blockIdx.x;               // bh*32 + kt, 1024 blocks
    int kt = blk & 31;
    int bh = blk >> 5;
    int b = bh >> 4, h = bh & 15;
    int tid = threadIdx.x;

    // ---- K part: thread -> (key=tid>>2, dim-octet qq=tid&3) ----
    {
        int key = tid >> 2, qq = tid & 3;
        int tglob = kt * 64 + key;
        const float* krow = K + ((size_t)(b * TT + tglob)) * HSZ + h * HD + qq * 8;
        float x0[8], x1[8];
        *(floatx4*)&x0[0] = *(const floatx4*)&krow[0];
        *(floatx4*)&x0[4] = *(const floatx4*)&krow[4];
        *(floatx4*)&x1[0] = *(const floatx4*)&krow[32];
        *(floatx4*)&x1[4] = *(const floatx4*)&krow[36];
        bf16x8 y0, y1;
        #pragma unroll
        for (int j = 0; j < 8; ++j) {
            float freq = exp2f((float)(qq * 8 + j) * NEGF);
            float rv = (float)tglob * freq * INV2PI;
            rv -= floorf(rv);
            float s = __builtin_amdgcn_sinf(rv);
            float c = __builtin_amdgcn_cosf(rv);
            y0[j] = (__bf16)(x0[j] * c - x1[j] * s);
            y1[j] = (__bf16)(x1[j] * c + x0[j] * s);
        }
        size_t base = ((size_t)blk * 4 + (key & 3)) * 1024 + (size_t)(qq * 16 + (key >> 2)) * 8;
        *(bf16x8*)(Kp + base)       = y0;
        *(bf16x8*)(Kp + base + 512) = y1;
    }

    // ---- V part: transpose 64x64 via LDS ----
    __shared__ __bf16 lt[64][72];
    {
        int vkey = tid >> 2, dg = (tid & 3) * 16;
        const float* vrow = V + ((size_t)(b * TT + kt * 64 + vkey)) * HSZ + h * HD + dg;
        floatx4 v0 = *(const floatx4*)&vrow[0];
        floatx4 v1 = *(const floatx4*)&vrow[4];
        floatx4 v2 = *(const floatx4*)&vrow[8];
        floatx4 v3 = *(const floatx4*)&vrow[12];
        #pragma unroll
        for (int j = 0; j < 4; ++j) {
            lt[dg + j][vkey]      = (__bf16)v0[j];
            lt[dg + 4 + j][vkey]  = (__bf16)v1[j];
            lt[dg + 8 + j][vkey]  = (__bf16)v2[j];
            lt[dg + 12 + j][vkey] = (__bf16)v3[j];
        }
    }
    __syncthreads();
    #pragma unroll
    for (int ss = 0; ss < 2; ++ss) {
        int s = tid + ss * 256;
        int hg = s >> 6;
        int l = s & 63;
        int lq = l >> 4, lr = l & 15;
        int h2 = hg >> 2, g = hg & 3;
        bf16x8 o = *(const bf16x8*)&lt[g * 16 + lr][h2 * 32 + lq * 8];
        *(bf16x8*)(Vp + (size_t)blk * 4096 + (size_t)hg * 512 + (size_t)l * 8) = o;
    }
}

// ============ phase 2: flash attention with ALiBi-sparsity tile skipping ============
// R5 structure (proven 58.4us) + per-head trailing-tile truncation:
// P ~ 2^(acc + slope2*k - ms); keys more than ~60/slope2 behind k=2047
// contribute < 2^-42 relative to the row max -> numerically zero at fp32
// and 13 orders below the 0.03 output tolerance. Head h needs only
// n_h = min(32, 41.58*2^((h+1)/2)/64 + 2) trailing tiles:
// {2,3,3,4,5,7,9,12,16,22,31,32,...} -> 53.5% of total work.
// Blocks dispatched heavy-first (rank-major) so round-robin CU fill
// balances: makespan ~32+tail equiv-iters vs 64 today.
__global__ __launch_bounds__(256, 2)
void attn_kernel(const float* __restrict__ Q, const __bf16* __restrict__ Kp,
                 const __bf16* __restrict__ Vp, float* __restrict__ Out) {
    int blk0 = blockIdx.x;              // 512 blocks: rank*32 + b*16 + qb
    int rank = blk0 >> 5;
    int h = (rank < 5) ? (11 + rank) : (15 - rank);   // descending n_h
    int rest = blk0 & 31;
    int b = rest >> 4;
    int qb = rest & 15;                 // 16 q-blocks of 128 rows
    int bh = b * 16 + h;
    int tid = threadIdx.x;
    int wave = tid >> 6, lane = tid & 63;
    int lane15 = lane & 15, quad = lane >> 4;

    // per-wave, per-qf P round-trip tiles; no __syncthreads anywhere
    __shared__ __align__(16) __bf16 sP[4][2][16][72];   // 18432 B

    const float scale2 = 0.125f * LOG2E;
    const float slope2 = exp2f(-0.5f * (float)(h + 1)) * LOG2E;
    const float ms     = slope2 * 2047.0f + 20.0f;      // static log2-domain shift

    // trailing tiles needed for this head (ALiBi decay budget E=60 log2 units)
    int nkt = (int)(41.58f * exp2f(0.5f * (float)(h + 1)) * (1.0f / 64.0f)) + 2;
    if (nkt > 32) nkt = 32;
    const int kt_beg = 32 - nkt;

    // ---- Q load + RoPE into 2 A-fragment pairs (32 q-rows/wave) ----
    int qbase = qb * 128 + wave * 32;
    int d0 = quad * 8;
    bf16x8 aQ0[2], aQ1[2];
    #pragma unroll
    for (int qf = 0; qf < 2; ++qf) {
        int t_q = qbase + qf * 16 + lane15;
        const float* qrow = Q + ((size_t)(b * TT + t_q) * HSZ) + h * HD;
        float q0[8], q1[8];
        *(floatx4*)&q0[0] = *(const floatx4*)&qrow[d0];
        *(floatx4*)&q0[4] = *(const floatx4*)&qrow[d0 + 4];
        *(floatx4*)&q1[0] = *(const floatx4*)&qrow[d0 + 32];
        *(floatx4*)&q1[4] = *(const floatx4*)&qrow[d0 + 36];
        #pragma unroll
        for (int j = 0; j < 8; ++j) {
            float freq = exp2f((float)(d0 + j) * NEGF);
            float rv = (float)t_q * freq * INV2PI;
            rv -= floorf(rv);
            float sn = __builtin_amdgcn_sinf(rv);
            float cs = __builtin_amdgcn_cosf(rv);
            aQ0[qf][j] = (__bf16)((q0[j] * cs - q1[j] * sn) * scale2);
            aQ1[qf][j] = (__bf16)((q1[j] * cs + q0[j] * sn) * scale2);
        }
    }

    float slk2[4];
    #pragma unroll
    for (int nt = 0; nt < 4; ++nt)
        slk2[nt] = slope2 * (float)(4 * lane15 + nt) - ms;
    const float dstep = slope2 * 64.0f;

    floatx4 O[2][4];
    float lrow[2][4];
    #pragma unroll
    for (int qf = 0; qf < 2; ++qf)
        #pragma unroll
        for (int r = 0; r < 4; ++r) {
            O[qf][r] = (floatx4){0.f, 0.f, 0.f, 0.f};
            lrow[qf][r] = 0.f;
        }

    const __bf16* Kb = Kp + (size_t)bh * (TT * HD) + (size_t)lane * 8;
    const __bf16* Vb = Vp + (size_t)bh * (TT * HD) + (size_t)lane * 8;

    const int kt1 = TT / 64;            // 32 tiles total

    // prologue: K fragments for first processed tile
    bf16x8 bk[4][2];
    {
        const __bf16* kbase = Kb + (size_t)kt_beg * 4096;
        #pragma unroll
        for (int nt = 0; nt < 4; ++nt) {
            bk[nt][0] = *(const bf16x8*)(kbase + nt * 1024);
            bk[nt][1] = *(const bf16x8*)(kbase + nt * 1024 + 512);
        }
    }

    #pragma unroll 1
    for (int kt = kt_beg; kt < kt1; ++kt) {
        // ---- V fragments for this tile (consumed in phase 2: latency hidden) ----
        const __bf16* vbase = Vb + (size_t)kt * 4096;
        bf16x8 bv[2][4];
        #pragma unroll
        for (int hg = 0; hg < 8; ++hg)
            bv[hg >> 2][hg & 3] = *(const bf16x8*)(vbase + hg * 512);

        // ---- phase 1: QK^T + exp2 + sP, for both q-fragments ----
        float biask = dstep * (float)kt;
        #pragma unroll
        for (int qf = 0; qf < 2; ++qf) {
            float P[4][4];
            #pragma unroll
            for (int nt = 0; nt < 4; ++nt) {
                floatx4 acc = {0.f, 0.f, 0.f, 0.f};
                acc = __builtin_amdgcn_mfma_f32_16x16x32_bf16(aQ0[qf], bk[nt][0], acc, 0, 0, 0);
                acc = __builtin_amdgcn_mfma_f32_16x16x32_bf16(aQ1[qf], bk[nt][1], acc, 0, 0, 0);
                float bias = slk2[nt] + biask;
                #pragma unroll
                for (int r = 0; r < 4; ++r)
                    P[nt][r] = __builtin_amdgcn_exp2f(acc[r] + bias);
            }
            #pragma unroll
            for (int r = 0; r < 4; ++r) {
                lrow[qf][r] += (P[0][r] + P[1][r]) + (P[2][r] + P[3][r]);
                bf16x4 pp;
                pp[0] = (__bf16)P[0][r]; pp[1] = (__bf16)P[1][r];
                pp[2] = (__bf16)P[2][r]; pp[3] = (__bf16)P[3][r];
                *(bf16x4*)&sP[wave][qf][quad * 4 + r][4 * lane15] = pp;
            }
        }

        // ---- prefetch K fragments for next tile (hidden under phase 2) ----
        if (kt + 1 < kt1) {
            const __bf16* kbase = Kb + (size_t)(kt + 1) * 4096;
            #pragma unroll
            for (int nt = 0; nt < 4; ++nt) {
                bk[nt][0] = *(const bf16x8*)(kbase + nt * 1024);
                bk[nt][1] = *(const bf16x8*)(kbase + nt * 1024 + 512);
            }
        }

        // ---- phase 2: PV for both q-fragments ----
        #pragma unroll
        for (int qf = 0; qf < 2; ++qf) {
            #pragma unroll
            for (int h2 = 0; h2 < 2; ++h2) {
                bf16x8 aP = *(const bf16x8*)&sP[wave][qf][lane15][h2 * 32 + quad * 8];
                O[qf][0] = __builtin_amdgcn_mfma_f32_16x16x32_bf16(aP, bv[h2][0], O[qf][0], 0, 0, 0);
                O[qf][1] = __builtin_amdgcn_mfma_f32_16x16x32_bf16(aP, bv[h2][1], O[qf][1], 0, 0, 0);
                O[qf][2] = __builtin_amdgcn_mfma_f32_16x16x32_bf16(aP, bv[h2][2], O[qf][2], 0, 0, 0);
                O[qf][3] = __builtin_amdgcn_mfma_f32_16x16x32_bf16(aP, bv[h2][3], O[qf][3], 0, 0, 0);
            }
        }
    }

    // ---- epilogue: reduce l, normalize in-register, write fp32 Out directly ----
    #pragma unroll
    for (int qf = 0; qf < 2; ++qf) {
        #pragma unroll
        for (int r = 0; r < 4; ++r) {
            float l = lrow[qf][r];
            l += __shfl_xor(l, 1);
            l += __shfl_xor(l, 2);
            l += __shfl_xor(l, 4);
            l += __shfl_xor(l, 8);
            float inv = 1.0f / l;
            int t = qbase + qf * 16 + quad * 4 + r;
            size_t base = ((size_t)(b * TT + t)) * HSZ + h * HD + lane15;
            Out[base +  0] = O[qf][0][r] * inv;
            Out[base + 16] = O[qf][1][r] * inv;
            Out[base + 32] = O[qf][2][r] * inv;
            Out[base + 48] = O[qf][3][r] * inv;
        }
    }
}

extern "C" void kernel_launch(void* const* d_in, const int* in_sizes, int n_in,
                              void* d_out, int out_size, void* d_ws, size_t ws_size,
                              hipStream_t stream) {
    const float* q = (const float*)d_in[0];
    const float* k = (const float*)d_in[1];
    const float* v = (const float*)d_in[2];
    float* out = (float*)d_out;

    char* ws = (char*)d_ws;
    __bf16* Kp = (__bf16*)ws;                                  // 8 MB
    __bf16* Vp = (__bf16*)(ws + (size_t)8 * 1024 * 1024);      // 8 MB

    prep_kernel<<<dim3(TB * NH * (TT / 64)), 256, 0, stream>>>(k, v, Kp, Vp);
    attn_kernel<<<dim3(TB * NH * 16), 256, 0, stream>>>(q, Kp, Vp, out);
}